// Round 1
// baseline (1805.637 us; speedup 1.0000x reference)
//
#include <hip/hip_runtime.h>
#include <math.h>

#define B_  4
#define L_  1024
#define DM  1024
#define DI  1024
#define DS  16
#define DR  64
#define DCV 4
#define NH  4
#define DK  256

// ---------------------------------------------------------------------------
// Depthwise causal conv1d + bias + SiLU:  u[b,l,d] = silu(sum_j xx[b,l-3+j,d]*w[d,j] + cb[d])
// ---------------------------------------------------------------------------
__global__ __launch_bounds__(256) void conv_silu_kernel(
    const float* __restrict__ xx, const float* __restrict__ cw,
    const float* __restrict__ cb, float* __restrict__ u)
{
    int idx = blockIdx.x * 256 + threadIdx.x;          // over B*L*DI
    int d = idx & (DI - 1);
    int l = (idx >> 10) & (L_ - 1);
    int b = idx >> 20;
    const float* xb = xx + (size_t)b * L_ * DI + d;
    float z = cb[d];
#pragma unroll
    for (int j = 0; j < DCV; j++) {
        int t = l - (DCV - 1) + j;
        if (t >= 0) z += xb[(size_t)t * DI] * cw[d * DCV + j];
    }
    u[idx] = z / (1.0f + __expf(-z));
}

// ---------------------------------------------------------------------------
// Generic fp32 GEMM: C[M,N] = act(A[M,K] @ W[N,K]^T + bias)
// 64x64 block tile, BK=16, 256 threads, 4x4 per-thread micro-tile.
// act: 0 = none, 1 = softplus
// ---------------------------------------------------------------------------
__global__ __launch_bounds__(256) void gemm_bt(
    const float* __restrict__ A, const float* __restrict__ W,
    const float* __restrict__ bias, float* __restrict__ C,
    int M, int N, int K, int lda, int ldc, int act)
{
    __shared__ __align__(16) float As[16][68];
    __shared__ __align__(16) float Ws[16][68];

    int tid = threadIdx.x;
    int bm = blockIdx.y * 64;
    int bn = blockIdx.x * 64;
    int tm = (tid & 15) * 4;      // row offset within tile
    int tn = (tid >> 4) * 4;      // col offset within tile

    int lr = tid >> 2;            // 0..63 : tile row loaded by this thread
    int lk = (tid & 3) * 4;       // 0..12 : k offset (float4)

    float acc[4][4] = {{0.f}};

    const float* Arow = A + (size_t)(bm + lr) * lda;
    const float* Wrow = W + (size_t)(bn + lr) * K;
    bool wvalid = (bn + lr) < N;

    for (int k0 = 0; k0 < K; k0 += 16) {
        float4 av = *(const float4*)(Arow + k0 + lk);
        float4 wv = make_float4(0.f, 0.f, 0.f, 0.f);
        if (wvalid) wv = *(const float4*)(Wrow + k0 + lk);
        As[lk + 0][lr] = av.x; As[lk + 1][lr] = av.y;
        As[lk + 2][lr] = av.z; As[lk + 3][lr] = av.w;
        Ws[lk + 0][lr] = wv.x; Ws[lk + 1][lr] = wv.y;
        Ws[lk + 2][lr] = wv.z; Ws[lk + 3][lr] = wv.w;
        __syncthreads();
#pragma unroll
        for (int kk = 0; kk < 16; kk++) {
            const float4 a = *(const float4*)&As[kk][tm];
            const float4 w = *(const float4*)&Ws[kk][tn];
            acc[0][0] += a.x * w.x; acc[0][1] += a.x * w.y; acc[0][2] += a.x * w.z; acc[0][3] += a.x * w.w;
            acc[1][0] += a.y * w.x; acc[1][1] += a.y * w.y; acc[1][2] += a.y * w.z; acc[1][3] += a.y * w.w;
            acc[2][0] += a.z * w.x; acc[2][1] += a.z * w.y; acc[2][2] += a.z * w.z; acc[2][3] += a.z * w.w;
            acc[3][0] += a.w * w.x; acc[3][1] += a.w * w.y; acc[3][2] += a.w * w.z; acc[3][3] += a.w * w.w;
        }
        __syncthreads();
    }

#pragma unroll
    for (int i = 0; i < 4; i++) {
        int row = bm + tm + i;
#pragma unroll
        for (int j = 0; j < 4; j++) {
            int col = bn + tn + j;
            if (col < N) {
                float v = acc[i][j];
                if (bias) v += bias[col];
                if (act == 1) v = (v > 15.f) ? v : log1pf(__expf(v));
                C[(size_t)row * ldc + col] = v;
            }
        }
    }
}

// ---------------------------------------------------------------------------
// Selective scan. One 16-lane group per (b,d); lane n owns state n.
// h = exp(delta*A[d,n])*h + (delta*u)*B[t,n];  y = sum_n h*C[t,n] + u*D[d]
// ---------------------------------------------------------------------------
__global__ __launch_bounds__(256) void scan_kernel(
    const float* __restrict__ delta, const float* __restrict__ u,
    const float* __restrict__ xdbl, const float* __restrict__ A_log,
    const float* __restrict__ Dv, float* __restrict__ y)
{
    int tid = threadIdx.x;
    int n = tid & 15;
    int gid = blockIdx.x * 16 + (tid >> 4);   // b*DI + d
    int b = gid >> 10;
    int d = gid & 1023;

    float a = -__expf(A_log[d * DS + n]);
    float Dd = Dv[d];
    float h = 0.f;

    const float* dp = delta + (size_t)b * L_ * DI + d;
    const float* up = u + (size_t)b * L_ * DI + d;
    const float* xp = xdbl + (size_t)b * L_ * 96;
    float* yp = y + (size_t)b * L_ * DI + d;

    for (int t = 0; t < L_; t++) {
        float dv = dp[(size_t)t * DI];
        float uv = up[(size_t)t * DI];
        float Bv = xp[t * 96 + DR + n];
        float Cv = xp[t * 96 + DR + DS + n];
        float dA = __expf(dv * a);
        h = dA * h + (dv * uv) * Bv;
        float p = h * Cv;
        p += __shfl_xor(p, 1);
        p += __shfl_xor(p, 2);
        p += __shfl_xor(p, 4);
        p += __shfl_xor(p, 8);
        if (n == 0) yp[(size_t)t * DI] = p + uv * Dd;
    }
}

// ---------------------------------------------------------------------------
// Transpose K (b,l,dm) -> KT (b,h,dk,l) for coalesced attention loads
// ---------------------------------------------------------------------------
__global__ __launch_bounds__(256) void transpose_k_kernel(
    const float* __restrict__ Kin, float* __restrict__ KT)
{
    int o = blockIdx.x * 256 + threadIdx.x;    // over B*NH*DK*L
    int l  = o & 1023;
    int kd = (o >> 10) & 255;
    int bh = o >> 18;                           // b*NH + h
    int b = bh >> 2, h = bh & 3;
    KT[o] = Kin[((size_t)(b * L_) + l) * DM + h * DK + kd];
}

// ---------------------------------------------------------------------------
// Fused attention: per block = (b, h, 8 query rows). Full softmax in LDS.
// ---------------------------------------------------------------------------
__global__ __launch_bounds__(256) void attn_kernel(
    const float* __restrict__ Q, const float* __restrict__ KT,
    const float* __restrict__ V, float* __restrict__ O)
{
    __shared__ float Qs[8][257];
    __shared__ float Ps[8][1025];

    int b = blockIdx.z, h = blockIdx.y;
    int r0 = blockIdx.x * 8;
    int tid = threadIdx.x;

    // load 8 Q rows (8*256 floats)
    for (int i = tid; i < 8 * 256; i += 256) {
        int r = i >> 8, c = i & 255;
        Qs[r][c] = Q[((size_t)(b * L_) + (r0 + r)) * DM + h * DK + c];
    }
    __syncthreads();

    int kg = tid & 63;        // key group: 4 consecutive keys
    int rg = tid >> 6;        // 0..3 -> rows rg*2, rg*2+1
    const float scale = 0.0625f;   // 1/sqrt(256)

    // phase 1: scores = Q K^T * scale
    for (int pass = 0; pass < 4; pass++) {
        int k0 = pass * 256 + kg * 4;
        float acc0[4] = {0.f, 0.f, 0.f, 0.f};
        float acc1[4] = {0.f, 0.f, 0.f, 0.f};
        const float* ktp = KT + ((size_t)(b * NH + h) * DK) * L_ + k0;
#pragma unroll 8
        for (int kd = 0; kd < DK; kd++) {
            float4 kv = *(const float4*)(ktp + (size_t)kd * L_);
            float q0 = Qs[rg * 2 + 0][kd];
            float q1 = Qs[rg * 2 + 1][kd];
            acc0[0] += q0 * kv.x; acc0[1] += q0 * kv.y; acc0[2] += q0 * kv.z; acc0[3] += q0 * kv.w;
            acc1[0] += q1 * kv.x; acc1[1] += q1 * kv.y; acc1[2] += q1 * kv.z; acc1[3] += q1 * kv.w;
        }
#pragma unroll
        for (int c = 0; c < 4; c++) {
            Ps[rg * 2 + 0][k0 + c] = acc0[c] * scale;
            Ps[rg * 2 + 1][k0 + c] = acc1[c] * scale;
        }
    }
    __syncthreads();

    // phase 2: softmax per row (32 threads / row)
    {
        int r = tid >> 5;
        int lane = tid & 31;
        float m = -1e30f;
        for (int k = lane; k < L_; k += 32) m = fmaxf(m, Ps[r][k]);
#pragma unroll
        for (int off = 16; off >= 1; off >>= 1) m = fmaxf(m, __shfl_xor(m, off));
        float s = 0.f;
        for (int k = lane; k < L_; k += 32) {
            float e = __expf(Ps[r][k] - m);
            Ps[r][k] = e;
            s += e;
        }
#pragma unroll
        for (int off = 16; off >= 1; off >>= 1) s += __shfl_xor(s, off);
        float inv = 1.0f / s;
        for (int k = lane; k < L_; k += 32) Ps[r][k] *= inv;
    }
    __syncthreads();

    // phase 3: out = P @ V
    {
        int dg = tid & 63;    // 4 consecutive dims
        float acc0[4] = {0.f, 0.f, 0.f, 0.f};
        float acc1[4] = {0.f, 0.f, 0.f, 0.f};
        const float* vp = V + (size_t)(b * L_) * DM + h * DK + dg * 4;
#pragma unroll 8
        for (int k = 0; k < L_; k++) {
            float4 vv = *(const float4*)(vp + (size_t)k * DM);
            float p0 = Ps[rg * 2 + 0][k];
            float p1 = Ps[rg * 2 + 1][k];
            acc0[0] += p0 * vv.x; acc0[1] += p0 * vv.y; acc0[2] += p0 * vv.z; acc0[3] += p0 * vv.w;
            acc1[0] += p1 * vv.x; acc1[1] += p1 * vv.y; acc1[2] += p1 * vv.z; acc1[3] += p1 * vv.w;
        }
        float* op0 = O + ((size_t)(b * L_) + (r0 + rg * 2 + 0)) * DM + h * DK + dg * 4;
        float* op1 = O + ((size_t)(b * L_) + (r0 + rg * 2 + 1)) * DM + h * DK + dg * 4;
#pragma unroll
        for (int c = 0; c < 4; c++) { op0[c] = acc0[c]; op1[c] = acc1[c]; }
    }
}

// ---------------------------------------------------------------------------
extern "C" void kernel_launch(void* const* d_in, const int* in_sizes, int n_in,
                              void* d_out, int out_size, void* d_ws, size_t ws_size,
                              hipStream_t stream)
{
    const float* x         = (const float*)d_in[0];
    const float* xx        = (const float*)d_in[1];
    const float* in_proj_w = (const float*)d_in[2];
    const float* conv_w    = (const float*)d_in[3];
    const float* conv_b    = (const float*)d_in[4];
    const float* x_proj_w  = (const float*)d_in[5];
    const float* dt_proj_w = (const float*)d_in[6];
    const float* dt_proj_b = (const float*)d_in[7];
    const float* A_log     = (const float*)d_in[8];
    const float* Dvec      = (const float*)d_in[9];
    const float* wq        = (const float*)d_in[10];
    const float* bq        = (const float*)d_in[11];
    const float* wk        = (const float*)d_in[12];
    const float* bk        = (const float*)d_in[13];
    const float* wv        = (const float*)d_in[14];
    const float* bv        = (const float*)d_in[15];
    const float* wo        = (const float*)d_in[16];
    const float* bo        = (const float*)d_in[17];
    float* out = (float*)d_out;

    float* ws = (float*)d_ws;
    const size_t SZ = (size_t)B_ * L_ * DM;   // 4M floats
    float* b_q     = ws;                      // q, later reused as KT
    float* b_u     = ws + SZ;                 // u, later reused as V
    float* b_xdbl  = ws + 2 * SZ;             // 0.5M floats
    float* b_delta = ws + 2 * SZ + SZ / 8;    // delta, later reused as K
    float* b_y     = ws + 3 * SZ + SZ / 8;
    float* b_Q     = ws + 4 * SZ + SZ / 8;
    float* b_ao    = ws + 5 * SZ + SZ / 8;

    dim3 blk(256);
    const int M = B_ * L_;    // 4096

    // 1. q = x @ in_proj_w^T
    gemm_bt<<<dim3(DM / 64, M / 64), blk, 0, stream>>>(x, in_proj_w, nullptr, b_q, M, DM, DM, DM, DM, 0);
    // 2. u = silu(causal depthwise conv(xx) + conv_b)
    conv_silu_kernel<<<dim3((B_ * L_ * DI) / 256), blk, 0, stream>>>(xx, conv_w, conv_b, b_u);
    // 3. x_dbl = u @ x_proj_w^T        (N=96)
    gemm_bt<<<dim3(2, M / 64), blk, 0, stream>>>(b_u, x_proj_w, nullptr, b_xdbl, M, 96, DI, DI, 96, 0);
    // 4. delta = softplus(x_dbl[:, :64] @ dt_proj_w^T + dt_proj_b)
    gemm_bt<<<dim3(DI / 64, M / 64), blk, 0, stream>>>(b_xdbl, dt_proj_w, dt_proj_b, b_delta, M, DI, DR, 96, DI, 1);
    // 5. selective scan -> y
    scan_kernel<<<dim3((B_ * DI) / 16), blk, 0, stream>>>(b_delta, b_u, b_xdbl, A_log, Dvec, b_y);
    // 6. Q, K, V projections
    gemm_bt<<<dim3(DM / 64, M / 64), blk, 0, stream>>>(b_q, wq, bq, b_Q, M, DM, DM, DM, DM, 0);
    gemm_bt<<<dim3(DM / 64, M / 64), blk, 0, stream>>>(b_y, wk, bk, b_delta, M, DM, DM, DM, DM, 0); // K -> b_delta
    gemm_bt<<<dim3(DM / 64, M / 64), blk, 0, stream>>>(b_y, wv, bv, b_u, M, DM, DM, DM, DM, 0);     // V -> b_u
    // 7. K -> KT (b,h,dk,l)   (after Q gemm consumed b_q)
    transpose_k_kernel<<<dim3((B_ * NH * DK * L_) / 256), blk, 0, stream>>>(b_delta, b_q);
    // 8. fused attention -> b_ao
    attn_kernel<<<dim3(L_ / 8, NH, B_), blk, 0, stream>>>(b_Q, b_q, b_u, b_ao);
    // 9. out = ao @ wo^T + bo
    gemm_bt<<<dim3(DM / 64, M / 64), blk, 0, stream>>>(b_ao, wo, bo, out, M, DM, DM, DM, DM, 0);
}

// Round 2
// 866.389 us; speedup vs baseline: 2.0841x; 2.0841x over previous
//
#include <hip/hip_runtime.h>
#include <math.h>

#define B_  4
#define L_  1024
#define DM  1024
#define DI  1024
#define DS  16
#define DR  64
#define DCV 4
#define NH  4
#define DK  256

typedef __attribute__((ext_vector_type(8))) short short8;
typedef __attribute__((ext_vector_type(4))) float floatx4;

static __device__ __forceinline__ unsigned short f2bf(float f) {
    unsigned int u = __float_as_uint(f);
    u += 0x7fffu + ((u >> 16) & 1u);          // round-to-nearest-even
    return (unsigned short)(u >> 16);
}
static __device__ __forceinline__ float bf2f(unsigned short s) {
    return __uint_as_float(((unsigned int)s) << 16);
}

// ---------------------------------------------------------------------------
// fp32 -> bf16 cast (n multiple of 4)
// ---------------------------------------------------------------------------
__global__ __launch_bounds__(256) void cast_f2bf(
    const float* __restrict__ s, unsigned short* __restrict__ d, int n)
{
    int i = (blockIdx.x * 256 + threadIdx.x) * 4;
    if (i < n) {
        float4 v = *(const float4*)(s + i);
        ushort4 o;
        o.x = f2bf(v.x); o.y = f2bf(v.y); o.z = f2bf(v.z); o.w = f2bf(v.w);
        *(ushort4*)(d + i) = o;
    }
}

// ---------------------------------------------------------------------------
// bf16 MFMA GEMM: C[M,N] = act(A[M,K] @ W[N,K]^T * scale + bias)
// 128x128 tile, BK=32, 256 threads (4 waves in 2x2), 16x16x32 MFMA, m97-style
// global_load_lds staging. M,N multiples of 128, K multiple of 32.
// Batched via grid.z: b = z>>2, h = z&3; operand offset = b*s1 + h*s2.
// ---------------------------------------------------------------------------
__global__ __launch_bounds__(256) void gemm_mfma(
    const unsigned short* __restrict__ A, const unsigned short* __restrict__ W,
    const float* __restrict__ bias, void* __restrict__ C,
    int K, int lda, int ldw, int ldc,
    long long sA1, long long sA2, long long sW1, long long sW2,
    long long sC1, long long sC2, float scale, int out_bf16)
{
    __shared__ __align__(16) unsigned short Asm[128 * 32];
    __shared__ __align__(16) unsigned short Bsm[128 * 32];

    int z = blockIdx.z;
    long long bq = z >> 2, hq = z & 3;
    int tid = threadIdx.x;
    int wid = tid >> 6;
    int lane = tid & 63;
    int wm = wid & 1, wn = wid >> 1;
    int lr = lane & 15, quad = lane >> 4;

    const unsigned short* Ab = A + bq * sA1 + hq * sA2 + (size_t)blockIdx.y * 128 * lda;
    const unsigned short* Wb = W + bq * sW1 + hq * sW2 + (size_t)blockIdx.x * 128 * ldw;

    // staging: thread t loads 16B: row t>>2 (0..63), col chunk (t&3)*8
    int srow = tid >> 2;
    int scol = (tid & 3) * 8;
    const unsigned short* Ap = Ab + (size_t)srow * lda + scol;
    const unsigned short* Wp = Wb + (size_t)srow * ldw + scol;

    // LDS destinations (wave-uniform): wave w, issue j -> rows j*64 + w*16 ..
    unsigned short* lA0 = &Asm[(wid * 16) * 32];
    unsigned short* lA1 = &Asm[(64 + wid * 16) * 32];
    unsigned short* lB0 = &Bsm[(wid * 16) * 32];
    unsigned short* lB1 = &Bsm[(64 + wid * 16) * 32];

    floatx4 acc[4][4];
#pragma unroll
    for (int i = 0; i < 4; i++)
#pragma unroll
        for (int j = 0; j < 4; j++) acc[i][j] = (floatx4){0.f, 0.f, 0.f, 0.f};

#define GLL(gp, lp) __builtin_amdgcn_global_load_lds( \
        (const __attribute__((address_space(1))) void*)(gp), \
        (__attribute__((address_space(3))) void*)(lp), 16, 0, 0)

    for (int k0 = 0; k0 < K; k0 += 32) {
        GLL(Ap, lA0);
        GLL(Ap + (size_t)64 * lda, lA1);
        GLL(Wp, lB0);
        GLL(Wp + (size_t)64 * ldw, lB1);
        Ap += 32; Wp += 32;
        __syncthreads();

        short8 af[4], bf[4];
#pragma unroll
        for (int mt = 0; mt < 4; mt++)
            af[mt] = *(const short8*)&Asm[(wm * 64 + mt * 16 + lr) * 32 + quad * 8];
#pragma unroll
        for (int nt = 0; nt < 4; nt++)
            bf[nt] = *(const short8*)&Bsm[(wn * 64 + nt * 16 + lr) * 32 + quad * 8];
#pragma unroll
        for (int mt = 0; mt < 4; mt++)
#pragma unroll
            for (int nt = 0; nt < 4; nt++)
                acc[mt][nt] = __builtin_amdgcn_mfma_f32_16x16x32_bf16(
                    af[mt], bf[nt], acc[mt][nt], 0, 0, 0);
        __syncthreads();
    }

    long long coff = bq * sC1 + hq * sC2;
    int bm = blockIdx.y * 128, bn = blockIdx.x * 128;
    unsigned short* Cb = (unsigned short*)C + coff;
    float* Cf = (float*)C + coff;

#pragma unroll
    for (int mt = 0; mt < 4; mt++) {
#pragma unroll
        for (int nt = 0; nt < 4; nt++) {
            int row0 = bm + wm * 64 + mt * 16 + quad * 4;
            int col = bn + wn * 64 + nt * 16 + lr;
            float bv = bias ? bias[col] : 0.f;
#pragma unroll
            for (int i = 0; i < 4; i++) {
                float v = acc[mt][nt][i] * scale + bv;
                if (out_bf16) Cb[(size_t)(row0 + i) * ldc + col] = f2bf(v);
                else          Cf[(size_t)(row0 + i) * ldc + col] = v;
            }
        }
    }
#undef GLL
}

// ---------------------------------------------------------------------------
// Depthwise causal conv1d + bias + SiLU (fp32)
// ---------------------------------------------------------------------------
__global__ __launch_bounds__(256) void conv_silu_kernel(
    const float* __restrict__ xx, const float* __restrict__ cw,
    const float* __restrict__ cb, float* __restrict__ u)
{
    int idx = blockIdx.x * 256 + threadIdx.x;
    int d = idx & (DI - 1);
    int l = (idx >> 10) & (L_ - 1);
    int b = idx >> 20;
    const float* xb = xx + (size_t)b * L_ * DI + d;
    float z = cb[d];
#pragma unroll
    for (int j = 0; j < DCV; j++) {
        int t = l - (DCV - 1) + j;
        if (t >= 0) z += xb[(size_t)t * DI] * cw[d * DCV + j];
    }
    u[idx] = z / (1.0f + __expf(-z));
}

// ---------------------------------------------------------------------------
// fp32 GEMM (small N / small K cases): C = act(A @ W^T + bias)
// ---------------------------------------------------------------------------
__global__ __launch_bounds__(256) void gemm_bt(
    const float* __restrict__ A, const float* __restrict__ W,
    const float* __restrict__ bias, float* __restrict__ C,
    int M, int N, int K, int lda, int ldc, int act)
{
    __shared__ __align__(16) float As[16][68];
    __shared__ __align__(16) float Ws[16][68];

    int tid = threadIdx.x;
    int bm = blockIdx.y * 64;
    int bn = blockIdx.x * 64;
    int tm = (tid & 15) * 4;
    int tn = (tid >> 4) * 4;
    int lr = tid >> 2;
    int lk = (tid & 3) * 4;

    float acc[4][4] = {{0.f}};
    const float* Arow = A + (size_t)(bm + lr) * lda;
    const float* Wrow = W + (size_t)(bn + lr) * K;
    bool wvalid = (bn + lr) < N;

    for (int k0 = 0; k0 < K; k0 += 16) {
        float4 av = *(const float4*)(Arow + k0 + lk);
        float4 wv = make_float4(0.f, 0.f, 0.f, 0.f);
        if (wvalid) wv = *(const float4*)(Wrow + k0 + lk);
        As[lk + 0][lr] = av.x; As[lk + 1][lr] = av.y;
        As[lk + 2][lr] = av.z; As[lk + 3][lr] = av.w;
        Ws[lk + 0][lr] = wv.x; Ws[lk + 1][lr] = wv.y;
        Ws[lk + 2][lr] = wv.z; Ws[lk + 3][lr] = wv.w;
        __syncthreads();
#pragma unroll
        for (int kk = 0; kk < 16; kk++) {
            const float4 a = *(const float4*)&As[kk][tm];
            const float4 w = *(const float4*)&Ws[kk][tn];
            acc[0][0] += a.x * w.x; acc[0][1] += a.x * w.y; acc[0][2] += a.x * w.z; acc[0][3] += a.x * w.w;
            acc[1][0] += a.y * w.x; acc[1][1] += a.y * w.y; acc[1][2] += a.y * w.z; acc[1][3] += a.y * w.w;
            acc[2][0] += a.z * w.x; acc[2][1] += a.z * w.y; acc[2][2] += a.z * w.z; acc[2][3] += a.z * w.w;
            acc[3][0] += a.w * w.x; acc[3][1] += a.w * w.y; acc[3][2] += a.w * w.z; acc[3][3] += a.w * w.w;
        }
        __syncthreads();
    }

#pragma unroll
    for (int i = 0; i < 4; i++) {
        int row = bm + tm + i;
#pragma unroll
        for (int j = 0; j < 4; j++) {
            int col = bn + tn + j;
            if (col < N) {
                float v = acc[i][j];
                if (bias) v += bias[col];
                if (act == 1) v = (v > 15.f) ? v : log1pf(__expf(v));
                C[(size_t)row * ldc + col] = v;
            }
        }
    }
}

// ---------------------------------------------------------------------------
// Selective scan (fp32 math), y written as bf16
// ---------------------------------------------------------------------------
__global__ __launch_bounds__(256) void scan_kernel(
    const float* __restrict__ delta, const float* __restrict__ u,
    const float* __restrict__ xdbl, const float* __restrict__ A_log,
    const float* __restrict__ Dv, unsigned short* __restrict__ y)
{
    int tid = threadIdx.x;
    int n = tid & 15;
    int gid = blockIdx.x * 16 + (tid >> 4);   // b*DI + d
    int b = gid >> 10;
    int d = gid & 1023;

    float a = -__expf(A_log[d * DS + n]);
    float Dd = Dv[d];
    float h = 0.f;

    const float* dp = delta + (size_t)b * L_ * DI + d;
    const float* up = u + (size_t)b * L_ * DI + d;
    const float* xp = xdbl + (size_t)b * L_ * 96;
    unsigned short* yp = y + (size_t)b * L_ * DI + d;

    for (int t = 0; t < L_; t++) {
        float dv = dp[(size_t)t * DI];
        float uv = up[(size_t)t * DI];
        float Bv = xp[t * 96 + DR + n];
        float Cv = xp[t * 96 + DR + DS + n];
        float dA = __expf(dv * a);
        h = dA * h + (dv * uv) * Bv;
        float p = h * Cv;
        p += __shfl_xor(p, 1);
        p += __shfl_xor(p, 2);
        p += __shfl_xor(p, 4);
        p += __shfl_xor(p, 8);
        if (n == 0) yp[(size_t)t * DI] = f2bf(p + uv * Dd);
    }
}

// ---------------------------------------------------------------------------
// V-half of KV [4096][2048] -> VT [bh][256][1024] (bf16 tiled transpose)
// grid (L/32, DK/32, 16)
// ---------------------------------------------------------------------------
__global__ __launch_bounds__(256) void transpose_v(
    const unsigned short* __restrict__ KV, unsigned short* __restrict__ VT)
{
    __shared__ unsigned short tl[32][36];
    int bh = blockIdx.z;
    int b = bh >> 2, h = bh & 3;
    int l0 = blockIdx.x * 32, d0 = blockIdx.y * 32;
    int tid = threadIdx.x;
    int r = tid >> 3, c4 = (tid & 7) * 4;

    const unsigned short* src = KV + ((size_t)(b * L_ + l0 + r)) * 2048 + 1024 + h * DK + d0 + c4;
    ushort4 v = *(const ushort4*)src;
    tl[r][c4 + 0] = v.x; tl[r][c4 + 1] = v.y; tl[r][c4 + 2] = v.z; tl[r][c4 + 3] = v.w;
    __syncthreads();

    unsigned short* dst = VT + ((size_t)bh * DK + d0 + r) * L_ + l0 + c4;
    ushort4 o;
    o.x = tl[c4 + 0][r]; o.y = tl[c4 + 1][r]; o.z = tl[c4 + 2][r]; o.w = tl[c4 + 3][r];
    *(ushort4*)dst = o;
}

// ---------------------------------------------------------------------------
// Row softmax over S [16*1024 rows][1024 cols] bf16, in place.
// 4 rows per block (1 wave per row).
// ---------------------------------------------------------------------------
__global__ __launch_bounds__(256) void softmax_rows(unsigned short* __restrict__ S)
{
    int row = blockIdx.x * 4 + (threadIdx.x >> 6);
    int lane = threadIdx.x & 63;
    unsigned short* p = S + (size_t)row * 1024;

    float v[16];
#pragma unroll
    for (int ch = 0; ch < 4; ch++) {
        ushort4 u4 = *(const ushort4*)(p + ch * 256 + lane * 4);
        v[ch * 4 + 0] = bf2f(u4.x); v[ch * 4 + 1] = bf2f(u4.y);
        v[ch * 4 + 2] = bf2f(u4.z); v[ch * 4 + 3] = bf2f(u4.w);
    }
    float m = -1e30f;
#pragma unroll
    for (int i = 0; i < 16; i++) m = fmaxf(m, v[i]);
#pragma unroll
    for (int off = 32; off >= 1; off >>= 1) m = fmaxf(m, __shfl_xor(m, off));
    float s = 0.f;
#pragma unroll
    for (int i = 0; i < 16; i++) { v[i] = __expf(v[i] - m); s += v[i]; }
#pragma unroll
    for (int off = 32; off >= 1; off >>= 1) s += __shfl_xor(s, off);
    float inv = 1.0f / s;
#pragma unroll
    for (int ch = 0; ch < 4; ch++) {
        ushort4 o;
        o.x = f2bf(v[ch * 4 + 0] * inv); o.y = f2bf(v[ch * 4 + 1] * inv);
        o.z = f2bf(v[ch * 4 + 2] * inv); o.w = f2bf(v[ch * 4 + 3] * inv);
        *(ushort4*)(p + ch * 256 + lane * 4) = o;
    }
}

// ---------------------------------------------------------------------------
extern "C" void kernel_launch(void* const* d_in, const int* in_sizes, int n_in,
                              void* d_out, int out_size, void* d_ws, size_t ws_size,
                              hipStream_t stream)
{
    const float* x         = (const float*)d_in[0];
    const float* xx        = (const float*)d_in[1];
    const float* in_proj_w = (const float*)d_in[2];
    const float* conv_w    = (const float*)d_in[3];
    const float* conv_b    = (const float*)d_in[4];
    const float* x_proj_w  = (const float*)d_in[5];
    const float* dt_proj_w = (const float*)d_in[6];
    const float* dt_proj_b = (const float*)d_in[7];
    const float* A_log     = (const float*)d_in[8];
    const float* Dvec      = (const float*)d_in[9];
    const float* wq        = (const float*)d_in[10];
    const float* bq        = (const float*)d_in[11];
    const float* wk        = (const float*)d_in[12];
    const float* bk        = (const float*)d_in[13];
    const float* wv        = (const float*)d_in[14];
    const float* bv        = (const float*)d_in[15];
    const float* wo        = (const float*)d_in[16];
    const float* bo        = (const float*)d_in[17];
    float* out = (float*)d_out;

    char* w = (char*)d_ws;
    const size_t MB = 1024 * 1024;
    float*          u_f   = (float*)(w + 0);             // 16 MB
    float*          delta = (float*)(w + 16 * MB);       // 16 MB
    unsigned short* Sbuf  = (unsigned short*)(w + 0);    // 32 MB (aliases u+delta, after scan)
    unsigned short* x_bf  = (unsigned short*)(w + 32 * MB);  // 8 MB, later Q_bf
    unsigned short* Q_bf  = x_bf;
    unsigned short* q_bf  = (unsigned short*)(w + 40 * MB);  // 8 MB, later VT
    unsigned short* VT    = q_bf;
    unsigned short* y_bf  = (unsigned short*)(w + 48 * MB);  // 8 MB, later AO
    unsigned short* AO    = y_bf;
    unsigned short* KV    = (unsigned short*)(w + 56 * MB);  // 16 MB
    float*          xdbl  = (float*)(w + 72 * MB);           // 1.5 MB
    unsigned short* w_in  = (unsigned short*)(w + 74 * MB);  // 2 MB
    unsigned short* w_qb  = (unsigned short*)(w + 76 * MB);  // 2 MB
    unsigned short* w_kv  = (unsigned short*)(w + 78 * MB);  // 4 MB
    unsigned short* w_ob  = (unsigned short*)(w + 82 * MB);  // 2 MB
    float*          bkv   = (float*)(w + 84 * MB);           // 8 KB

    dim3 blk(256);
    const int M = B_ * L_;    // 4096
    const long long LL = L_;

    // weight / input casts
    cast_f2bf<<<dim3(4096), blk, 0, stream>>>(x, x_bf, M * DM);
    cast_f2bf<<<dim3(1024), blk, 0, stream>>>(in_proj_w, w_in, DM * DI);
    cast_f2bf<<<dim3(1024), blk, 0, stream>>>(wq, w_qb, DM * DM);
    cast_f2bf<<<dim3(1024), blk, 0, stream>>>(wk, w_kv, DM * DM);
    cast_f2bf<<<dim3(1024), blk, 0, stream>>>(wv, w_kv + DM * DM, DM * DM);
    cast_f2bf<<<dim3(1024), blk, 0, stream>>>(wo, w_ob, DM * DM);
    hipMemcpyAsync(bkv, bk, DM * sizeof(float), hipMemcpyDeviceToDevice, stream);
    hipMemcpyAsync(bkv + DM, bv, DM * sizeof(float), hipMemcpyDeviceToDevice, stream);

    // 1. q = x @ in_proj_w^T   (bf16 out)
    gemm_mfma<<<dim3(8, 32, 1), blk, 0, stream>>>(x_bf, w_in, nullptr, q_bf,
        DM, DM, DM, DM, 0, 0, 0, 0, 0, 0, 1.0f, 1);
    // 2. u = silu(conv(xx))
    conv_silu_kernel<<<dim3(16384), blk, 0, stream>>>(xx, conv_w, conv_b, u_f);
    // 3. x_dbl = u @ x_proj_w^T
    gemm_bt<<<dim3(2, 64), blk, 0, stream>>>(u_f, x_proj_w, nullptr, xdbl, M, 96, DI, DI, 96, 0);
    // 4. delta = softplus(x_dbl[:, :64] @ dt_proj_w^T + b)
    gemm_bt<<<dim3(16, 64), blk, 0, stream>>>(xdbl, dt_proj_w, dt_proj_b, delta, M, DI, DR, 96, DI, 1);
    // 5. scan -> y (bf16)
    scan_kernel<<<dim3(256), blk, 0, stream>>>(delta, u_f, xdbl, A_log, Dvec, y_bf);
    // 6. Q = q @ wq^T + bq  (bf16) ; KV = y @ [wk;wv]^T + [bk;bv]
    gemm_mfma<<<dim3(8, 32, 1), blk, 0, stream>>>(q_bf, w_qb, bq, Q_bf,
        DM, DM, DM, DM, 0, 0, 0, 0, 0, 0, 1.0f, 1);
    gemm_mfma<<<dim3(16, 32, 1), blk, 0, stream>>>(y_bf, w_kv, bkv, KV,
        DM, DM, DM, 2048, 0, 0, 0, 0, 0, 0, 1.0f, 1);
    // 7. VT[bh][dk][l] from V half of KV
    transpose_v<<<dim3(32, 8, 16), blk, 0, stream>>>(KV, VT);
    // 8. S = Q @ K^T * scale  (batched over 16 bh)
    gemm_mfma<<<dim3(8, 8, 16), blk, 0, stream>>>(Q_bf, KV, nullptr, Sbuf,
        DK, DM, 2048, 1024,
        LL * 1024, 256,                 // A: b*L*1024 + h*256
        LL * 2048, 256,                 // W(K): b*L*2048 + h*256
        4 * LL * 1024, LL * 1024,       // C(S): z*L*1024
        0.0625f, 1);
    // 9. softmax rows of S
    softmax_rows<<<dim3(4096), blk, 0, stream>>>(Sbuf);
    // 10. AO = P @ V   (W = VT)
    gemm_mfma<<<dim3(2, 8, 16), blk, 0, stream>>>(Sbuf, VT, nullptr, AO,
        1024, 1024, 1024, 1024,
        4 * LL * 1024, LL * 1024,       // A(P): z*L*1024
        4 * (long long)DK * 1024, (long long)DK * 1024,  // W(VT): z*DK*1024
        LL * 1024, 256,                 // C(AO): b*L*1024 + h*256
        1.0f, 1);
    // 11. out = AO @ wo^T + bo   (fp32 out)
    gemm_mfma<<<dim3(8, 32, 1), blk, 0, stream>>>(AO, w_ob, bo, out,
        DM, DM, DM, DM, 0, 0, 0, 0, 0, 0, 1.0f, 0);
}

// Round 3
// 541.339 us; speedup vs baseline: 3.3355x; 1.6005x over previous
//
#include <hip/hip_runtime.h>
#include <math.h>

#define B_  4
#define L_  1024
#define DM  1024
#define DI  1024
#define DS  16
#define DR  64
#define DCV 4
#define NH  4
#define DK  256

#define NCH 8          // scan time-chunks
#define CHL (L_ / NCH) // 128 steps per chunk

typedef __attribute__((ext_vector_type(8))) short short8;
typedef __attribute__((ext_vector_type(4))) float floatx4;

static __device__ __forceinline__ unsigned short f2bf(float f) {
    unsigned int u = __float_as_uint(f);
    u += 0x7fffu + ((u >> 16) & 1u);          // round-to-nearest-even
    return (unsigned short)(u >> 16);
}
static __device__ __forceinline__ float bf2f(unsigned short s) {
    return __uint_as_float(((unsigned int)s) << 16);
}

// ---------------------------------------------------------------------------
// fp32 -> bf16 cast (n multiple of 4)
// ---------------------------------------------------------------------------
__global__ __launch_bounds__(256) void cast_f2bf(
    const float* __restrict__ s, unsigned short* __restrict__ d, int n)
{
    int i = (blockIdx.x * 256 + threadIdx.x) * 4;
    if (i < n) {
        float4 v = *(const float4*)(s + i);
        ushort4 o;
        o.x = f2bf(v.x); o.y = f2bf(v.y); o.z = f2bf(v.z); o.w = f2bf(v.w);
        *(ushort4*)(d + i) = o;
    }
}

// ---------------------------------------------------------------------------
// bf16 MFMA GEMM: C[M,N] = A[M,K] @ W[N,K]^T * scale + bias
// 128x128 tile, BK=32, 256 threads (4 waves 2x2), 16x16x32 MFMA,
// global_load_lds width-16 staging. Batched via grid.z (b=z>>2, h=z&3).
// ---------------------------------------------------------------------------
__global__ __launch_bounds__(256) void gemm_mfma(
    const unsigned short* __restrict__ A, const unsigned short* __restrict__ W,
    const float* __restrict__ bias, void* __restrict__ C,
    int K, int lda, int ldw, int ldc,
    long long sA1, long long sA2, long long sW1, long long sW2,
    long long sC1, long long sC2, float scale, int out_bf16)
{
    __shared__ __align__(16) unsigned short Asm[128 * 32];
    __shared__ __align__(16) unsigned short Bsm[128 * 32];

    int z = blockIdx.z;
    long long bq = z >> 2, hq = z & 3;
    int tid = threadIdx.x;
    int wid = tid >> 6;
    int lane = tid & 63;
    int wm = wid & 1, wn = wid >> 1;
    int lr = lane & 15, quad = lane >> 4;

    const unsigned short* Ab = A + bq * sA1 + hq * sA2 + (size_t)blockIdx.y * 128 * lda;
    const unsigned short* Wb = W + bq * sW1 + hq * sW2 + (size_t)blockIdx.x * 128 * ldw;

    int srow = tid >> 2;
    int scol = (tid & 3) * 8;
    const unsigned short* Ap = Ab + (size_t)srow * lda + scol;
    const unsigned short* Wp = Wb + (size_t)srow * ldw + scol;

    unsigned short* lA0 = &Asm[(wid * 16) * 32];
    unsigned short* lA1 = &Asm[(64 + wid * 16) * 32];
    unsigned short* lB0 = &Bsm[(wid * 16) * 32];
    unsigned short* lB1 = &Bsm[(64 + wid * 16) * 32];

    floatx4 acc[4][4];
#pragma unroll
    for (int i = 0; i < 4; i++)
#pragma unroll
        for (int j = 0; j < 4; j++) acc[i][j] = (floatx4){0.f, 0.f, 0.f, 0.f};

#define GLL(gp, lp) __builtin_amdgcn_global_load_lds( \
        (const __attribute__((address_space(1))) void*)(gp), \
        (__attribute__((address_space(3))) void*)(lp), 16, 0, 0)

    for (int k0 = 0; k0 < K; k0 += 32) {
        GLL(Ap, lA0);
        GLL(Ap + (size_t)64 * lda, lA1);
        GLL(Wp, lB0);
        GLL(Wp + (size_t)64 * ldw, lB1);
        Ap += 32; Wp += 32;
        __syncthreads();

        short8 af[4], bf[4];
#pragma unroll
        for (int mt = 0; mt < 4; mt++)
            af[mt] = *(const short8*)&Asm[(wm * 64 + mt * 16 + lr) * 32 + quad * 8];
#pragma unroll
        for (int nt = 0; nt < 4; nt++)
            bf[nt] = *(const short8*)&Bsm[(wn * 64 + nt * 16 + lr) * 32 + quad * 8];
#pragma unroll
        for (int mt = 0; mt < 4; mt++)
#pragma unroll
            for (int nt = 0; nt < 4; nt++)
                acc[mt][nt] = __builtin_amdgcn_mfma_f32_16x16x32_bf16(
                    af[mt], bf[nt], acc[mt][nt], 0, 0, 0);
        __syncthreads();
    }

    long long coff = bq * sC1 + hq * sC2;
    int bm = blockIdx.y * 128, bn = blockIdx.x * 128;
    unsigned short* Cb = (unsigned short*)C + coff;
    float* Cf = (float*)C + coff;

#pragma unroll
    for (int mt = 0; mt < 4; mt++) {
#pragma unroll
        for (int nt = 0; nt < 4; nt++) {
            int row0 = bm + wm * 64 + mt * 16 + quad * 4;
            int col = bn + wn * 64 + nt * 16 + lr;
            float bv = bias ? bias[col] : 0.f;
#pragma unroll
            for (int i = 0; i < 4; i++) {
                float v = acc[mt][nt][i] * scale + bv;
                if (out_bf16) Cb[(size_t)(row0 + i) * ldc + col] = f2bf(v);
                else          Cf[(size_t)(row0 + i) * ldc + col] = v;
            }
        }
    }
#undef GLL
}

// ---------------------------------------------------------------------------
// Depthwise causal conv1d + bias + SiLU (fp32)
// ---------------------------------------------------------------------------
__global__ __launch_bounds__(256) void conv_silu_kernel(
    const float* __restrict__ xx, const float* __restrict__ cw,
    const float* __restrict__ cb, float* __restrict__ u)
{
    int idx = blockIdx.x * 256 + threadIdx.x;
    int d = idx & (DI - 1);
    int l = (idx >> 10) & (L_ - 1);
    int b = idx >> 20;
    const float* xb = xx + (size_t)b * L_ * DI + d;
    float z = cb[d];
#pragma unroll
    for (int j = 0; j < DCV; j++) {
        int t = l - (DCV - 1) + j;
        if (t >= 0) z += xb[(size_t)t * DI] * cw[d * DCV + j];
    }
    u[idx] = z / (1.0f + __expf(-z));
}

// ---------------------------------------------------------------------------
// fp32 GEMM (small N / small K): C = act(A @ W^T + bias), act 1 = softplus
// ---------------------------------------------------------------------------
__global__ __launch_bounds__(256) void gemm_bt(
    const float* __restrict__ A, const float* __restrict__ W,
    const float* __restrict__ bias, float* __restrict__ C,
    int M, int N, int K, int lda, int ldc, int act)
{
    __shared__ __align__(16) float As[16][68];
    __shared__ __align__(16) float Ws[16][68];

    int tid = threadIdx.x;
    int bm = blockIdx.y * 64;
    int bn = blockIdx.x * 64;
    int tm = (tid & 15) * 4;
    int tn = (tid >> 4) * 4;
    int lr = tid >> 2;
    int lk = (tid & 3) * 4;

    float acc[4][4] = {{0.f}};
    const float* Arow = A + (size_t)(bm + lr) * lda;
    const float* Wrow = W + (size_t)(bn + lr) * K;
    bool wvalid = (bn + lr) < N;

    for (int k0 = 0; k0 < K; k0 += 16) {
        float4 av = *(const float4*)(Arow + k0 + lk);
        float4 wv = make_float4(0.f, 0.f, 0.f, 0.f);
        if (wvalid) wv = *(const float4*)(Wrow + k0 + lk);
        As[lk + 0][lr] = av.x; As[lk + 1][lr] = av.y;
        As[lk + 2][lr] = av.z; As[lk + 3][lr] = av.w;
        Ws[lk + 0][lr] = wv.x; Ws[lk + 1][lr] = wv.y;
        Ws[lk + 2][lr] = wv.z; Ws[lk + 3][lr] = wv.w;
        __syncthreads();
#pragma unroll
        for (int kk = 0; kk < 16; kk++) {
            const float4 a = *(const float4*)&As[kk][tm];
            const float4 w = *(const float4*)&Ws[kk][tn];
            acc[0][0] += a.x * w.x; acc[0][1] += a.x * w.y; acc[0][2] += a.x * w.z; acc[0][3] += a.x * w.w;
            acc[1][0] += a.y * w.x; acc[1][1] += a.y * w.y; acc[1][2] += a.y * w.z; acc[1][3] += a.y * w.w;
            acc[2][0] += a.z * w.x; acc[2][1] += a.z * w.y; acc[2][2] += a.z * w.z; acc[2][3] += a.z * w.w;
            acc[3][0] += a.w * w.x; acc[3][1] += a.w * w.y; acc[3][2] += a.w * w.z; acc[3][3] += a.w * w.w;
        }
        __syncthreads();
    }

#pragma unroll
    for (int i = 0; i < 4; i++) {
        int row = bm + tm + i;
#pragma unroll
        for (int j = 0; j < 4; j++) {
            int col = bn + tn + j;
            if (col < N) {
                float v = acc[i][j];
                if (bias) v += bias[col];
                if (act == 1) v = (v > 15.f) ? v : log1pf(__expf(v));
                C[(size_t)row * ldc + col] = v;
            }
        }
    }
}

// ---------------------------------------------------------------------------
// Chunked selective scan.
// Phase A: per (b,d,chunk) local scan (h0=0) -> Hc[bd][c][n], sumdv[bd][c]
// ---------------------------------------------------------------------------
__global__ __launch_bounds__(256) void scan_phase_a(
    const float* __restrict__ delta, const float* __restrict__ u,
    const float* __restrict__ xdbl, const float* __restrict__ A_log,
    float* __restrict__ Hc, float* __restrict__ sumdv)
{
    int tid = threadIdx.x;
    int n = tid & 15;
    int bd = blockIdx.x * 16 + (tid >> 4);
    int c = blockIdx.y;
    int b = bd >> 10;
    int d = bd & 1023;

    float a = -__expf(A_log[d * DS + n]);
    float h = 0.f, sd = 0.f;
    int t0 = c * CHL;

    const float* dp = delta + ((size_t)b * L_ + t0) * DI + d;
    const float* up = u + ((size_t)b * L_ + t0) * DI + d;
    const float* xp = xdbl + ((size_t)b * L_ + t0) * 96;

    for (int t = 0; t < CHL; t++) {
        float dv = dp[(size_t)t * DI];
        float uv = up[(size_t)t * DI];
        float Bv = xp[t * 96 + DR + n];
        sd += dv;
        h = __expf(dv * a) * h + (dv * uv) * Bv;
    }
    Hc[((size_t)bd * NCH + c) * DS + n] = h;
    if (n == 0) sumdv[(size_t)bd * NCH + c] = sd;
}

// ---------------------------------------------------------------------------
// Phase B: sequential combine across chunks -> Hstart[bd][c][n]
// ---------------------------------------------------------------------------
__global__ __launch_bounds__(256) void scan_combine(
    const float* __restrict__ Hc, const float* __restrict__ sumdv,
    const float* __restrict__ A_log, float* __restrict__ Hstart)
{
    int tid = threadIdx.x;
    int n = tid & 15;
    int bd = blockIdx.x * 16 + (tid >> 4);
    int d = bd & 1023;

    float a = -__expf(A_log[d * DS + n]);
    float H = 0.f;
#pragma unroll
    for (int c = 0; c < NCH; c++) {
        size_t o = ((size_t)bd * NCH + c) * DS + n;
        Hstart[o] = H;
        float P = __expf(a * sumdv[(size_t)bd * NCH + c]);
        H = P * H + Hc[o];
    }
}

// ---------------------------------------------------------------------------
// Phase C: re-run each chunk from Hstart, emit y (bf16)
// ---------------------------------------------------------------------------
__global__ __launch_bounds__(256) void scan_phase_c(
    const float* __restrict__ delta, const float* __restrict__ u,
    const float* __restrict__ xdbl, const float* __restrict__ A_log,
    const float* __restrict__ Dv, const float* __restrict__ Hstart,
    unsigned short* __restrict__ y)
{
    int tid = threadIdx.x;
    int n = tid & 15;
    int bd = blockIdx.x * 16 + (tid >> 4);
    int c = blockIdx.y;
    int b = bd >> 10;
    int d = bd & 1023;

    float a = -__expf(A_log[d * DS + n]);
    float Dd = Dv[d];
    float h = Hstart[((size_t)bd * NCH + c) * DS + n];
    int t0 = c * CHL;

    const float* dp = delta + ((size_t)b * L_ + t0) * DI + d;
    const float* up = u + ((size_t)b * L_ + t0) * DI + d;
    const float* xp = xdbl + ((size_t)b * L_ + t0) * 96;
    unsigned short* yp = y + ((size_t)b * L_ + t0) * DI + d;

    for (int t = 0; t < CHL; t++) {
        float dv = dp[(size_t)t * DI];
        float uv = up[(size_t)t * DI];
        float Bv = xp[t * 96 + DR + n];
        float Cv = xp[t * 96 + DR + DS + n];
        h = __expf(dv * a) * h + (dv * uv) * Bv;
        float p = h * Cv;
        p += __shfl_xor(p, 1);
        p += __shfl_xor(p, 2);
        p += __shfl_xor(p, 4);
        p += __shfl_xor(p, 8);
        if (n == 0) yp[(size_t)t * DI] = f2bf(p + uv * Dd);
    }
}

// ---------------------------------------------------------------------------
// V-half of KV [4096][2048] -> VT [bh][256][1024] (bf16 tiled transpose)
// ---------------------------------------------------------------------------
__global__ __launch_bounds__(256) void transpose_v(
    const unsigned short* __restrict__ KV, unsigned short* __restrict__ VT)
{
    __shared__ unsigned short tl[32][36];
    int bh = blockIdx.z;
    int b = bh >> 2, h = bh & 3;
    int l0 = blockIdx.x * 32, d0 = blockIdx.y * 32;
    int tid = threadIdx.x;
    int r = tid >> 3, c4 = (tid & 7) * 4;

    const unsigned short* src = KV + ((size_t)(b * L_ + l0 + r)) * 2048 + 1024 + h * DK + d0 + c4;
    ushort4 v = *(const ushort4*)src;
    tl[r][c4 + 0] = v.x; tl[r][c4 + 1] = v.y; tl[r][c4 + 2] = v.z; tl[r][c4 + 3] = v.w;
    __syncthreads();

    unsigned short* dst = VT + ((size_t)bh * DK + d0 + r) * L_ + l0 + c4;
    ushort4 o;
    o.x = tl[c4 + 0][r]; o.y = tl[c4 + 1][r]; o.z = tl[c4 + 2][r]; o.w = tl[c4 + 3][r];
    *(ushort4*)dst = o;
}

// ---------------------------------------------------------------------------
// Row softmax over S [16*1024 rows][1024 cols] bf16, in place.
// ---------------------------------------------------------------------------
__global__ __launch_bounds__(256) void softmax_rows(unsigned short* __restrict__ S)
{
    int row = blockIdx.x * 4 + (threadIdx.x >> 6);
    int lane = threadIdx.x & 63;
    unsigned short* p = S + (size_t)row * 1024;

    float v[16];
#pragma unroll
    for (int ch = 0; ch < 4; ch++) {
        ushort4 u4 = *(const ushort4*)(p + ch * 256 + lane * 4);
        v[ch * 4 + 0] = bf2f(u4.x); v[ch * 4 + 1] = bf2f(u4.y);
        v[ch * 4 + 2] = bf2f(u4.z); v[ch * 4 + 3] = bf2f(u4.w);
    }
    float m = -1e30f;
#pragma unroll
    for (int i = 0; i < 16; i++) m = fmaxf(m, v[i]);
#pragma unroll
    for (int off = 32; off >= 1; off >>= 1) m = fmaxf(m, __shfl_xor(m, off));
    float s = 0.f;
#pragma unroll
    for (int i = 0; i < 16; i++) { v[i] = __expf(v[i] - m); s += v[i]; }
#pragma unroll
    for (int off = 32; off >= 1; off >>= 1) s += __shfl_xor(s, off);
    float inv = 1.0f / s;
#pragma unroll
    for (int ch = 0; ch < 4; ch++) {
        ushort4 o;
        o.x = f2bf(v[ch * 4 + 0] * inv); o.y = f2bf(v[ch * 4 + 1] * inv);
        o.z = f2bf(v[ch * 4 + 2] * inv); o.w = f2bf(v[ch * 4 + 3] * inv);
        *(ushort4*)(p + ch * 256 + lane * 4) = o;
    }
}

// ---------------------------------------------------------------------------
extern "C" void kernel_launch(void* const* d_in, const int* in_sizes, int n_in,
                              void* d_out, int out_size, void* d_ws, size_t ws_size,
                              hipStream_t stream)
{
    const float* x         = (const float*)d_in[0];
    const float* xx        = (const float*)d_in[1];
    const float* in_proj_w = (const float*)d_in[2];
    const float* conv_w    = (const float*)d_in[3];
    const float* conv_b    = (const float*)d_in[4];
    const float* x_proj_w  = (const float*)d_in[5];
    const float* dt_proj_w = (const float*)d_in[6];
    const float* dt_proj_b = (const float*)d_in[7];
    const float* A_log     = (const float*)d_in[8];
    const float* Dvec      = (const float*)d_in[9];
    const float* wq        = (const float*)d_in[10];
    const float* bq        = (const float*)d_in[11];
    const float* wk        = (const float*)d_in[12];
    const float* bk        = (const float*)d_in[13];
    const float* wv        = (const float*)d_in[14];
    const float* bv        = (const float*)d_in[15];
    const float* wo        = (const float*)d_in[16];
    const float* bo        = (const float*)d_in[17];
    float* out = (float*)d_out;

    char* w = (char*)d_ws;
    const size_t MB = 1024 * 1024;
    float*          u_f   = (float*)(w + 0);             // 16 MB
    float*          delta = (float*)(w + 16 * MB);       // 16 MB
    unsigned short* Sbuf  = (unsigned short*)(w + 0);    // 32 MB (aliases u+delta, after scan)
    unsigned short* x_bf  = (unsigned short*)(w + 32 * MB);  // 8 MB, later Q_bf
    unsigned short* Q_bf  = x_bf;
    unsigned short* q_bf  = (unsigned short*)(w + 40 * MB);  // 8 MB, later VT
    unsigned short* VT    = q_bf;
    unsigned short* y_bf  = (unsigned short*)(w + 48 * MB);  // 8 MB, later AO
    unsigned short* AO    = y_bf;
    unsigned short* KV    = (unsigned short*)(w + 56 * MB);  // 16 MB
    float*          xdbl  = (float*)(w + 72 * MB);           // 1.5 MB
    unsigned short* w_in  = (unsigned short*)(w + 74 * MB);  // 2 MB
    unsigned short* w_qb  = (unsigned short*)(w + 76 * MB);  // 2 MB
    unsigned short* w_kv  = (unsigned short*)(w + 78 * MB);  // 4 MB
    unsigned short* w_ob  = (unsigned short*)(w + 82 * MB);  // 2 MB
    float*          bkv   = (float*)(w + 84 * MB);           // 8 KB
    float*          Hc    = (float*)(w + 85 * MB);           // 2 MB
    float*          Hstart= (float*)(w + 87 * MB);           // 2 MB
    float*          sumdv = (float*)(w + 89 * MB);           // 128 KB

    dim3 blk(256);
    const int M = B_ * L_;    // 4096
    const long long LL = L_;

    // weight / input casts
    cast_f2bf<<<dim3(4096), blk, 0, stream>>>(x, x_bf, M * DM);
    cast_f2bf<<<dim3(1024), blk, 0, stream>>>(in_proj_w, w_in, DM * DI);
    cast_f2bf<<<dim3(1024), blk, 0, stream>>>(wq, w_qb, DM * DM);
    cast_f2bf<<<dim3(1024), blk, 0, stream>>>(wk, w_kv, DM * DM);
    cast_f2bf<<<dim3(1024), blk, 0, stream>>>(wv, w_kv + DM * DM, DM * DM);
    cast_f2bf<<<dim3(1024), blk, 0, stream>>>(wo, w_ob, DM * DM);
    hipMemcpyAsync(bkv, bk, DM * sizeof(float), hipMemcpyDeviceToDevice, stream);
    hipMemcpyAsync(bkv + DM, bv, DM * sizeof(float), hipMemcpyDeviceToDevice, stream);

    // 1. q = x @ in_proj_w^T   (bf16 out)
    gemm_mfma<<<dim3(8, 32, 1), blk, 0, stream>>>(x_bf, w_in, nullptr, q_bf,
        DM, DM, DM, DM, 0, 0, 0, 0, 0, 0, 1.0f, 1);
    // 2. u = silu(conv(xx))
    conv_silu_kernel<<<dim3(16384), blk, 0, stream>>>(xx, conv_w, conv_b, u_f);
    // 3. x_dbl = u @ x_proj_w^T
    gemm_bt<<<dim3(2, 64), blk, 0, stream>>>(u_f, x_proj_w, nullptr, xdbl, M, 96, DI, DI, 96, 0);
    // 4. delta = softplus(x_dbl[:, :64] @ dt_proj_w^T + b)
    gemm_bt<<<dim3(16, 64), blk, 0, stream>>>(xdbl, dt_proj_w, dt_proj_b, delta, M, DI, DR, 96, DI, 1);
    // 5. chunked scan -> y (bf16)
    scan_phase_a<<<dim3(256, NCH), blk, 0, stream>>>(delta, u_f, xdbl, A_log, Hc, sumdv);
    scan_combine<<<dim3(256), blk, 0, stream>>>(Hc, sumdv, A_log, Hstart);
    scan_phase_c<<<dim3(256, NCH), blk, 0, stream>>>(delta, u_f, xdbl, A_log, Dvec, Hstart, y_bf);
    // 6. Q = q @ wq^T + bq  (bf16) ; KV = y @ [wk;wv]^T + [bk;bv]
    gemm_mfma<<<dim3(8, 32, 1), blk, 0, stream>>>(q_bf, w_qb, bq, Q_bf,
        DM, DM, DM, DM, 0, 0, 0, 0, 0, 0, 1.0f, 1);
    gemm_mfma<<<dim3(16, 32, 1), blk, 0, stream>>>(y_bf, w_kv, bkv, KV,
        DM, DM, DM, 2048, 0, 0, 0, 0, 0, 0, 1.0f, 1);
    // 7. VT[bh][dk][l] from V half of KV
    transpose_v<<<dim3(32, 8, 16), blk, 0, stream>>>(KV, VT);
    // 8. S = Q @ K^T * scale  (batched over 16 bh)
    gemm_mfma<<<dim3(8, 8, 16), blk, 0, stream>>>(Q_bf, KV, nullptr, Sbuf,
        DK, DM, 2048, 1024,
        LL * 1024, 256,
        LL * 2048, 256,
        4 * LL * 1024, LL * 1024,
        0.0625f, 1);
    // 9. softmax rows of S
    softmax_rows<<<dim3(4096), blk, 0, stream>>>(Sbuf);
    // 10. AO = P @ V   (W = VT)
    gemm_mfma<<<dim3(2, 8, 16), blk, 0, stream>>>(Sbuf, VT, nullptr, AO,
        1024, 1024, 1024, 1024,
        4 * LL * 1024, LL * 1024,
        4 * (long long)DK * 1024, (long long)DK * 1024,
        LL * 1024, 256,
        1.0f, 1);
    // 11. out = AO @ wo^T + bo   (fp32 out)
    gemm_mfma<<<dim3(8, 32, 1), blk, 0, stream>>>(AO, w_ob, bo, out,
        DM, DM, DM, DM, 0, 0, 0, 0, 0, 0, 1.0f, 0);
}

// Round 4
// 441.536 us; speedup vs baseline: 4.0894x; 1.2260x over previous
//
#include <hip/hip_runtime.h>
#include <math.h>

#define B_  4
#define L_  1024
#define DM  1024
#define DI  1024
#define DS  16
#define DR  64
#define DCV 4
#define NH  4
#define DK  256

#define NCH 32         // scan time-chunks
#define CHL (L_ / NCH) // 32 steps per chunk

typedef __attribute__((ext_vector_type(8))) short short8;
typedef __attribute__((ext_vector_type(4))) float floatx4;

static __device__ __forceinline__ unsigned short f2bf(float f) {
    unsigned int u = __float_as_uint(f);
    u += 0x7fffu + ((u >> 16) & 1u);
    return (unsigned short)(u >> 16);
}
static __device__ __forceinline__ float bf2f(unsigned short s) {
    return __uint_as_float(((unsigned int)s) << 16);
}

// ---------------------------------------------------------------------------
// Fused fp32->bf16 casts (8 regions, grid.y selects; pads with zeros past ns)
// ---------------------------------------------------------------------------
struct CastArgs {
    const float* s[8];
    unsigned short* d[8];
    int n[8];   // output element count (mult of 4)
    int ns[8];  // source element count (<= n, rest zero-padded)
};

__global__ __launch_bounds__(256) void cast_multi(CastArgs ca)
{
    int y = blockIdx.y;
    int i = (blockIdx.x * 256 + threadIdx.x) * 4;
    if (i >= ca.n[y]) return;
    const float* s = ca.s[y];
    unsigned short* d = ca.d[y];
    int ns = ca.ns[y];
    ushort4 o;
    if (i + 4 <= ns) {
        float4 v = *(const float4*)(s + i);
        o.x = f2bf(v.x); o.y = f2bf(v.y); o.z = f2bf(v.z); o.w = f2bf(v.w);
    } else {
        float v[4];
#pragma unroll
        for (int j = 0; j < 4; j++) v[j] = (i + j < ns) ? s[i + j] : 0.f;
        o.x = f2bf(v[0]); o.y = f2bf(v[1]); o.z = f2bf(v[2]); o.w = f2bf(v[3]);
    }
    *(ushort4*)(d + i) = o;
}

// ---------------------------------------------------------------------------
// Multi-descriptor bf16 MFMA GEMM: per z, C = act(A @ W^T * scale + bias)
// 128x128 tile, BK=32, 256 threads, 16x16x32 MFMA, global_load_lds staging.
// mode & 3: 0 = fp32 out, 1 = bf16 out, 2 = both. mode & 4: softplus.
// ---------------------------------------------------------------------------
struct GDesc {
    const unsigned short* A;
    const unsigned short* W;
    const float* bias;
    float* Cf;
    unsigned short* Cb;
    int K, lda, ldw, ldc, ldc2;
    int mode;
    float scale;
    int gx, gy;
};
struct GArgs { GDesc g[3]; };

__global__ __launch_bounds__(256) void gemm_multi(GArgs ga)
{
    GDesc g = ga.g[blockIdx.z];
    if ((int)blockIdx.x >= g.gx || (int)blockIdx.y >= g.gy) return;

    __shared__ __align__(16) unsigned short Asm[128 * 32];
    __shared__ __align__(16) unsigned short Bsm[128 * 32];

    int tid = threadIdx.x;
    int wid = tid >> 6;
    int lane = tid & 63;
    int wm = wid & 1, wn = wid >> 1;
    int lr = lane & 15, quad = lane >> 4;

    const unsigned short* Ab = g.A + (size_t)blockIdx.y * 128 * g.lda;
    const unsigned short* Wb = g.W + (size_t)blockIdx.x * 128 * g.ldw;

    int srow = tid >> 2;
    int scol = (tid & 3) * 8;
    const unsigned short* Ap = Ab + (size_t)srow * g.lda + scol;
    const unsigned short* Wp = Wb + (size_t)srow * g.ldw + scol;

    unsigned short* lA0 = &Asm[(wid * 16) * 32];
    unsigned short* lA1 = &Asm[(64 + wid * 16) * 32];
    unsigned short* lB0 = &Bsm[(wid * 16) * 32];
    unsigned short* lB1 = &Bsm[(64 + wid * 16) * 32];

    floatx4 acc[4][4];
#pragma unroll
    for (int i = 0; i < 4; i++)
#pragma unroll
        for (int j = 0; j < 4; j++) acc[i][j] = (floatx4){0.f, 0.f, 0.f, 0.f};

#define GLL(gp, lp) __builtin_amdgcn_global_load_lds( \
        (const __attribute__((address_space(1))) void*)(gp), \
        (__attribute__((address_space(3))) void*)(lp), 16, 0, 0)

    for (int k0 = 0; k0 < g.K; k0 += 32) {
        GLL(Ap, lA0);
        GLL(Ap + (size_t)64 * g.lda, lA1);
        GLL(Wp, lB0);
        GLL(Wp + (size_t)64 * g.ldw, lB1);
        Ap += 32; Wp += 32;
        __syncthreads();

        short8 af[4], bf[4];
#pragma unroll
        for (int mt = 0; mt < 4; mt++)
            af[mt] = *(const short8*)&Asm[(wm * 64 + mt * 16 + lr) * 32 + quad * 8];
#pragma unroll
        for (int nt = 0; nt < 4; nt++)
            bf[nt] = *(const short8*)&Bsm[(wn * 64 + nt * 16 + lr) * 32 + quad * 8];
#pragma unroll
        for (int mt = 0; mt < 4; mt++)
#pragma unroll
            for (int nt = 0; nt < 4; nt++)
                acc[mt][nt] = __builtin_amdgcn_mfma_f32_16x16x32_bf16(
                    af[mt], bf[nt], acc[mt][nt], 0, 0, 0);
        __syncthreads();
    }
#undef GLL

    int bm = blockIdx.y * 128, bn = blockIdx.x * 128;
    int m = g.mode & 3;
#pragma unroll
    for (int mt = 0; mt < 4; mt++) {
#pragma unroll
        for (int nt = 0; nt < 4; nt++) {
            int row0 = bm + wm * 64 + mt * 16 + quad * 4;
            int col = bn + wn * 64 + nt * 16 + lr;
            float bv = g.bias ? g.bias[col] : 0.f;
#pragma unroll
            for (int i = 0; i < 4; i++) {
                float v = acc[mt][nt][i] * g.scale + bv;
                if (g.mode & 4) v = (v > 15.f) ? v : log1pf(__expf(v));
                if (m == 0) {
                    g.Cf[(size_t)(row0 + i) * g.ldc + col] = v;
                } else if (m == 1) {
                    g.Cb[(size_t)(row0 + i) * g.ldc + col] = f2bf(v);
                } else {
                    g.Cf[(size_t)(row0 + i) * g.ldc + col] = v;
                    g.Cb[(size_t)(row0 + i) * g.ldc2 + col] = f2bf(v);
                }
            }
        }
    }
}

// ---------------------------------------------------------------------------
// Batched-strided bf16 MFMA GEMM (attention): z -> b=z>>2, h=z&3
// ---------------------------------------------------------------------------
__global__ __launch_bounds__(256) void gemm_batched(
    const unsigned short* __restrict__ A, const unsigned short* __restrict__ W,
    unsigned short* __restrict__ C,
    int K, int lda, int ldw, int ldc,
    long long sA1, long long sA2, long long sW1, long long sW2,
    long long sC1, long long sC2, float scale)
{
    __shared__ __align__(16) unsigned short Asm[128 * 32];
    __shared__ __align__(16) unsigned short Bsm[128 * 32];

    int z = blockIdx.z;
    long long bq = z >> 2, hq = z & 3;
    int tid = threadIdx.x;
    int wid = tid >> 6;
    int lane = tid & 63;
    int wm = wid & 1, wn = wid >> 1;
    int lr = lane & 15, quad = lane >> 4;

    const unsigned short* Ab = A + bq * sA1 + hq * sA2 + (size_t)blockIdx.y * 128 * lda;
    const unsigned short* Wb = W + bq * sW1 + hq * sW2 + (size_t)blockIdx.x * 128 * ldw;

    int srow = tid >> 2;
    int scol = (tid & 3) * 8;
    const unsigned short* Ap = Ab + (size_t)srow * lda + scol;
    const unsigned short* Wp = Wb + (size_t)srow * ldw + scol;

    unsigned short* lA0 = &Asm[(wid * 16) * 32];
    unsigned short* lA1 = &Asm[(64 + wid * 16) * 32];
    unsigned short* lB0 = &Bsm[(wid * 16) * 32];
    unsigned short* lB1 = &Bsm[(64 + wid * 16) * 32];

    floatx4 acc[4][4];
#pragma unroll
    for (int i = 0; i < 4; i++)
#pragma unroll
        for (int j = 0; j < 4; j++) acc[i][j] = (floatx4){0.f, 0.f, 0.f, 0.f};

#define GLL(gp, lp) __builtin_amdgcn_global_load_lds( \
        (const __attribute__((address_space(1))) void*)(gp), \
        (__attribute__((address_space(3))) void*)(lp), 16, 0, 0)

    for (int k0 = 0; k0 < K; k0 += 32) {
        GLL(Ap, lA0);
        GLL(Ap + (size_t)64 * lda, lA1);
        GLL(Wp, lB0);
        GLL(Wp + (size_t)64 * ldw, lB1);
        Ap += 32; Wp += 32;
        __syncthreads();

        short8 af[4], bf[4];
#pragma unroll
        for (int mt = 0; mt < 4; mt++)
            af[mt] = *(const short8*)&Asm[(wm * 64 + mt * 16 + lr) * 32 + quad * 8];
#pragma unroll
        for (int nt = 0; nt < 4; nt++)
            bf[nt] = *(const short8*)&Bsm[(wn * 64 + nt * 16 + lr) * 32 + quad * 8];
#pragma unroll
        for (int mt = 0; mt < 4; mt++)
#pragma unroll
            for (int nt = 0; nt < 4; nt++)
                acc[mt][nt] = __builtin_amdgcn_mfma_f32_16x16x32_bf16(
                    af[mt], bf[nt], acc[mt][nt], 0, 0, 0);
        __syncthreads();
    }
#undef GLL

    long long coff = bq * sC1 + hq * sC2;
    int bm = blockIdx.y * 128, bn = blockIdx.x * 128;
    unsigned short* Cb = C + coff;

#pragma unroll
    for (int mt = 0; mt < 4; mt++) {
#pragma unroll
        for (int nt = 0; nt < 4; nt++) {
            int row0 = bm + wm * 64 + mt * 16 + quad * 4;
            int col = bn + wn * 64 + nt * 16 + lr;
#pragma unroll
            for (int i = 0; i < 4; i++)
                Cb[(size_t)(row0 + i) * ldc + col] = f2bf(acc[mt][nt][i] * scale);
        }
    }
}

// ---------------------------------------------------------------------------
// Depthwise causal conv1d + bias + SiLU; writes fp32 u and bf16 u
// ---------------------------------------------------------------------------
__global__ __launch_bounds__(256) void conv_silu_kernel(
    const float* __restrict__ xx, const float* __restrict__ cw,
    const float* __restrict__ cb, float* __restrict__ u,
    unsigned short* __restrict__ ub)
{
    int idx = blockIdx.x * 256 + threadIdx.x;
    int d = idx & (DI - 1);
    int l = (idx >> 10) & (L_ - 1);
    int b = idx >> 20;
    const float* xb = xx + (size_t)b * L_ * DI + d;
    float z = cb[d];
#pragma unroll
    for (int j = 0; j < DCV; j++) {
        int t = l - (DCV - 1) + j;
        if (t >= 0) z += xb[(size_t)t * DI] * cw[d * DCV + j];
    }
    float v = z / (1.0f + __expf(-z));
    u[idx] = v;
    ub[idx] = f2bf(v);
}

// ---------------------------------------------------------------------------
// Scan phase A: one thread = (b,d,chunk), 16 states in registers.
// Hc layout [c][bd][16], sumdv [c][bd].
// ---------------------------------------------------------------------------
__global__ __launch_bounds__(256) void scan_a(
    const float* __restrict__ delta, const float* __restrict__ u,
    const float* __restrict__ xdbl, const float* __restrict__ A_log,
    float* __restrict__ Hc, float* __restrict__ sumdv)
{
    int gid = blockIdx.x * 256 + threadIdx.x;   // 131072
    int c = gid >> 12;
    int bd = gid & 4095;
    int b = bd >> 10, d = bd & 1023;

    float a[16];
#pragma unroll
    for (int j = 0; j < 4; j++) {
        float4 al = *(const float4*)(A_log + d * 16 + j * 4);
        a[j * 4 + 0] = -__expf(al.x); a[j * 4 + 1] = -__expf(al.y);
        a[j * 4 + 2] = -__expf(al.z); a[j * 4 + 3] = -__expf(al.w);
    }
    float h[16];
#pragma unroll
    for (int n = 0; n < 16; n++) h[n] = 0.f;
    float sd = 0.f;

    int t0 = c * CHL;
    const float* dp = delta + ((size_t)(b * L_) + t0) * DI + d;
    const float* up = u + ((size_t)(b * L_) + t0) * DI + d;
    const float* xp = xdbl + ((size_t)(b * L_) + t0) * 128;

#pragma unroll 4
    for (int t = 0; t < CHL; t++) {
        float dv = dp[t * DI];
        float uv = up[t * DI];
        float duv = dv * uv;
        sd += dv;
        float Bv[16];
#pragma unroll
        for (int j = 0; j < 4; j++) {
            float4 bq = *(const float4*)(xp + t * 128 + 64 + j * 4);
            Bv[j * 4 + 0] = bq.x; Bv[j * 4 + 1] = bq.y;
            Bv[j * 4 + 2] = bq.z; Bv[j * 4 + 3] = bq.w;
        }
#pragma unroll
        for (int n = 0; n < 16; n++)
            h[n] = __expf(dv * a[n]) * h[n] + duv * Bv[n];
    }

    float* hp = Hc + ((size_t)c * 4096 + bd) * 16;
#pragma unroll
    for (int j = 0; j < 4; j++)
        *(float4*)(hp + j * 4) = make_float4(h[j * 4], h[j * 4 + 1], h[j * 4 + 2], h[j * 4 + 3]);
    sumdv[c * 4096 + bd] = sd;
}

// ---------------------------------------------------------------------------
// Scan phase B: in-place combine — Hc[c][bd][*] becomes the chunk's START state
// ---------------------------------------------------------------------------
__global__ __launch_bounds__(256) void scan_b(
    float* __restrict__ Hc, const float* __restrict__ sumdv,
    const float* __restrict__ A_log)
{
    int bd = blockIdx.x * 256 + threadIdx.x;   // 4096
    int d = bd & 1023;

    float a[16];
#pragma unroll
    for (int j = 0; j < 4; j++) {
        float4 al = *(const float4*)(A_log + d * 16 + j * 4);
        a[j * 4 + 0] = -__expf(al.x); a[j * 4 + 1] = -__expf(al.y);
        a[j * 4 + 2] = -__expf(al.z); a[j * 4 + 3] = -__expf(al.w);
    }
    float H[16];
#pragma unroll
    for (int n = 0; n < 16; n++) H[n] = 0.f;

    for (int c = 0; c < NCH; c++) {
        float* hp = Hc + ((size_t)c * 4096 + bd) * 16;
        float sdv = sumdv[c * 4096 + bd];
        float hc[16];
#pragma unroll
        for (int j = 0; j < 4; j++) {
            float4 q = *(const float4*)(hp + j * 4);
            hc[j * 4 + 0] = q.x; hc[j * 4 + 1] = q.y; hc[j * 4 + 2] = q.z; hc[j * 4 + 3] = q.w;
        }
#pragma unroll
        for (int j = 0; j < 4; j++)
            *(float4*)(hp + j * 4) = make_float4(H[j * 4], H[j * 4 + 1], H[j * 4 + 2], H[j * 4 + 3]);
#pragma unroll
        for (int n = 0; n < 16; n++)
            H[n] = __expf(a[n] * sdv) * H[n] + hc[n];
    }
}

// ---------------------------------------------------------------------------
// Scan phase C: re-run chunk from start state, emit y (bf16)
// ---------------------------------------------------------------------------
__global__ __launch_bounds__(256) void scan_c(
    const float* __restrict__ delta, const float* __restrict__ u,
    const float* __restrict__ xdbl, const float* __restrict__ A_log,
    const float* __restrict__ Dv, const float* __restrict__ Hstart,
    unsigned short* __restrict__ y)
{
    int gid = blockIdx.x * 256 + threadIdx.x;
    int c = gid >> 12;
    int bd = gid & 4095;
    int b = bd >> 10, d = bd & 1023;

    float a[16];
#pragma unroll
    for (int j = 0; j < 4; j++) {
        float4 al = *(const float4*)(A_log + d * 16 + j * 4);
        a[j * 4 + 0] = -__expf(al.x); a[j * 4 + 1] = -__expf(al.y);
        a[j * 4 + 2] = -__expf(al.z); a[j * 4 + 3] = -__expf(al.w);
    }
    float h[16];
    const float* hp = Hstart + ((size_t)c * 4096 + bd) * 16;
#pragma unroll
    for (int j = 0; j < 4; j++) {
        float4 q = *(const float4*)(hp + j * 4);
        h[j * 4 + 0] = q.x; h[j * 4 + 1] = q.y; h[j * 4 + 2] = q.z; h[j * 4 + 3] = q.w;
    }
    float Dd = Dv[d];

    int t0 = c * CHL;
    const float* dp = delta + ((size_t)(b * L_) + t0) * DI + d;
    const float* up = u + ((size_t)(b * L_) + t0) * DI + d;
    const float* xp = xdbl + ((size_t)(b * L_) + t0) * 128;
    unsigned short* yp = y + ((size_t)(b * L_) + t0) * DI + d;

#pragma unroll 4
    for (int t = 0; t < CHL; t++) {
        float dv = dp[t * DI];
        float uv = up[t * DI];
        float duv = dv * uv;
        float Bv[16], Cv[16];
#pragma unroll
        for (int j = 0; j < 4; j++) {
            float4 bq = *(const float4*)(xp + t * 128 + 64 + j * 4);
            Bv[j * 4 + 0] = bq.x; Bv[j * 4 + 1] = bq.y;
            Bv[j * 4 + 2] = bq.z; Bv[j * 4 + 3] = bq.w;
            float4 cq = *(const float4*)(xp + t * 128 + 80 + j * 4);
            Cv[j * 4 + 0] = cq.x; Cv[j * 4 + 1] = cq.y;
            Cv[j * 4 + 2] = cq.z; Cv[j * 4 + 3] = cq.w;
        }
        float ys = 0.f;
#pragma unroll
        for (int n = 0; n < 16; n++) {
            h[n] = __expf(dv * a[n]) * h[n] + duv * Bv[n];
            ys += h[n] * Cv[n];
        }
        yp[t * DI] = f2bf(ys + uv * Dd);
    }
}

// ---------------------------------------------------------------------------
// V [4096][1024] -> VT [bh][256][1024] (bf16 tiled transpose)
// ---------------------------------------------------------------------------
__global__ __launch_bounds__(256) void transpose_v(
    const unsigned short* __restrict__ V, unsigned short* __restrict__ VT)
{
    __shared__ unsigned short tl[32][36];
    int bh = blockIdx.z;
    int b = bh >> 2, h = bh & 3;
    int l0 = blockIdx.x * 32, d0 = blockIdx.y * 32;
    int tid = threadIdx.x;
    int r = tid >> 3, c4 = (tid & 7) * 4;

    const unsigned short* src = V + ((size_t)(b * L_ + l0 + r)) * 1024 + h * DK + d0 + c4;
    ushort4 v = *(const ushort4*)src;
    tl[r][c4 + 0] = v.x; tl[r][c4 + 1] = v.y; tl[r][c4 + 2] = v.z; tl[r][c4 + 3] = v.w;
    __syncthreads();

    unsigned short* dst = VT + ((size_t)bh * DK + d0 + r) * L_ + l0 + c4;
    ushort4 o;
    o.x = tl[c4 + 0][r]; o.y = tl[c4 + 1][r]; o.z = tl[c4 + 2][r]; o.w = tl[c4 + 3][r];
    *(ushort4*)dst = o;
}

// ---------------------------------------------------------------------------
// Row softmax over S [16384 rows][1024 cols] bf16, in place.
// ---------------------------------------------------------------------------
__global__ __launch_bounds__(256) void softmax_rows(unsigned short* __restrict__ S)
{
    int row = blockIdx.x * 4 + (threadIdx.x >> 6);
    int lane = threadIdx.x & 63;
    unsigned short* p = S + (size_t)row * 1024;

    float v[16];
#pragma unroll
    for (int ch = 0; ch < 4; ch++) {
        ushort4 u4 = *(const ushort4*)(p + ch * 256 + lane * 4);
        v[ch * 4 + 0] = bf2f(u4.x); v[ch * 4 + 1] = bf2f(u4.y);
        v[ch * 4 + 2] = bf2f(u4.z); v[ch * 4 + 3] = bf2f(u4.w);
    }
    float m = -1e30f;
#pragma unroll
    for (int i = 0; i < 16; i++) m = fmaxf(m, v[i]);
#pragma unroll
    for (int off = 32; off >= 1; off >>= 1) m = fmaxf(m, __shfl_xor(m, off));
    float s = 0.f;
#pragma unroll
    for (int i = 0; i < 16; i++) { v[i] = __expf(v[i] - m); s += v[i]; }
#pragma unroll
    for (int off = 32; off >= 1; off >>= 1) s += __shfl_xor(s, off);
    float inv = 1.0f / s;
#pragma unroll
    for (int ch = 0; ch < 4; ch++) {
        ushort4 o;
        o.x = f2bf(v[ch * 4 + 0] * inv); o.y = f2bf(v[ch * 4 + 1] * inv);
        o.z = f2bf(v[ch * 4 + 2] * inv); o.w = f2bf(v[ch * 4 + 3] * inv);
        *(ushort4*)(p + ch * 256 + lane * 4) = o;
    }
}

// ---------------------------------------------------------------------------
extern "C" void kernel_launch(void* const* d_in, const int* in_sizes, int n_in,
                              void* d_out, int out_size, void* d_ws, size_t ws_size,
                              hipStream_t stream)
{
    const float* x         = (const float*)d_in[0];
    const float* xx        = (const float*)d_in[1];
    const float* in_proj_w = (const float*)d_in[2];
    const float* conv_w    = (const float*)d_in[3];
    const float* conv_b    = (const float*)d_in[4];
    const float* x_proj_w  = (const float*)d_in[5];
    const float* dt_proj_w = (const float*)d_in[6];
    const float* dt_proj_b = (const float*)d_in[7];
    const float* A_log     = (const float*)d_in[8];
    const float* Dvec      = (const float*)d_in[9];
    const float* wq        = (const float*)d_in[10];
    const float* bq        = (const float*)d_in[11];
    const float* wk        = (const float*)d_in[12];
    const float* bk        = (const float*)d_in[13];
    const float* wv        = (const float*)d_in[14];
    const float* bv        = (const float*)d_in[15];
    const float* wo        = (const float*)d_in[16];
    const float* bo        = (const float*)d_in[17];
    float* out = (float*)d_out;

    char* w = (char*)d_ws;
    const size_t MB = 1024 * 1024, KB = 1024;
    float*          u_f    = (float*)(w + 0);              // 16 MB
    float*          delta  = (float*)(w + 16 * MB);        // 16 MB
    unsigned short* Sbuf   = (unsigned short*)(w + 0);     // 32 MB, after scan
    unsigned short* x_bf   = (unsigned short*)(w + 32 * MB); // 8 MB -> Q_bf
    unsigned short* Q_bf   = x_bf;
    unsigned short* q_bf   = (unsigned short*)(w + 40 * MB); // 8 MB -> VT
    unsigned short* VT     = q_bf;
    unsigned short* y_bf   = (unsigned short*)(w + 48 * MB); // 8 MB -> AO
    unsigned short* AO     = y_bf;
    unsigned short* K_bf   = (unsigned short*)(w + 56 * MB); // 8 MB
    unsigned short* V_bf   = (unsigned short*)(w + 64 * MB); // 8 MB
    unsigned short* u_bf   = (unsigned short*)(w + 72 * MB); // 8 MB -> Hc
    float*          Hc     = (float*)(w + 72 * MB);
    float*          xdbl   = (float*)(w + 80 * MB);          // 2 MB
    unsigned short* xdblb  = (unsigned short*)(w + 82 * MB); // 1 MB
    unsigned short* w_in   = (unsigned short*)(w + 83 * MB); // 2 MB
    unsigned short* w_q    = (unsigned short*)(w + 85 * MB); // 2 MB
    unsigned short* w_k    = (unsigned short*)(w + 87 * MB); // 2 MB
    unsigned short* w_v    = (unsigned short*)(w + 89 * MB); // 2 MB
    unsigned short* w_o    = (unsigned short*)(w + 91 * MB); // 2 MB
    unsigned short* w_xp   = (unsigned short*)(w + 93 * MB);            // 256 KB
    unsigned short* w_dt   = (unsigned short*)(w + 93 * MB + 256 * KB); // 128 KB
    float*          sumdv  = (float*)(w + 93 * MB + 384 * KB);          // 512 KB

    dim3 blk(256);
    const long long LL = L_;

    // 1. fused casts
    CastArgs ca;
    ca.s[0] = x;         ca.d[0] = x_bf;  ca.n[0] = 4194304; ca.ns[0] = 4194304;
    ca.s[1] = in_proj_w; ca.d[1] = w_in;  ca.n[1] = 1048576; ca.ns[1] = 1048576;
    ca.s[2] = wq;        ca.d[2] = w_q;   ca.n[2] = 1048576; ca.ns[2] = 1048576;
    ca.s[3] = wk;        ca.d[3] = w_k;   ca.n[3] = 1048576; ca.ns[3] = 1048576;
    ca.s[4] = wv;        ca.d[4] = w_v;   ca.n[4] = 1048576; ca.ns[4] = 1048576;
    ca.s[5] = wo;        ca.d[5] = w_o;   ca.n[5] = 1048576; ca.ns[5] = 1048576;
    ca.s[6] = x_proj_w;  ca.d[6] = w_xp;  ca.n[6] = 131072;  ca.ns[6] = 98304;
    ca.s[7] = dt_proj_w; ca.d[7] = w_dt;  ca.n[7] = 65536;   ca.ns[7] = 65536;
    cast_multi<<<dim3(4096, 8), blk, 0, stream>>>(ca);

    // 2. conv + silu
    conv_silu_kernel<<<dim3(16384), blk, 0, stream>>>(xx, conv_w, conv_b, u_f, u_bf);

    // 3. in_proj || x_proj
    {
        GArgs ga = {};
        ga.g[0] = (GDesc){x_bf, w_in, nullptr, nullptr, q_bf,
                          1024, 1024, 1024, 1024, 0, 1, 1.0f, 8, 32};
        ga.g[1] = (GDesc){u_bf, w_xp, nullptr, xdbl, xdblb,
                          1024, 1024, 1024, 128, 128, 2, 1.0f, 1, 32};
        gemm_multi<<<dim3(8, 32, 2), blk, 0, stream>>>(ga);
    }
    // 4. dt_proj (softplus)
    {
        GArgs ga = {};
        ga.g[0] = (GDesc){xdblb, w_dt, dt_proj_b, delta, nullptr,
                          64, 128, 64, 1024, 0, 0 | 4, 1.0f, 8, 32};
        gemm_multi<<<dim3(8, 32, 1), blk, 0, stream>>>(ga);
    }
    // 5-7. chunked scan
    scan_a<<<dim3(512), blk, 0, stream>>>(delta, u_f, xdbl, A_log, Hc, sumdv);
    scan_b<<<dim3(16), blk, 0, stream>>>(Hc, sumdv, A_log);
    scan_c<<<dim3(512), blk, 0, stream>>>(delta, u_f, xdbl, A_log, Dvec, Hc, y_bf);

    // 8. Q || K || V projections
    {
        GArgs ga = {};
        ga.g[0] = (GDesc){q_bf, w_q, bq, nullptr, Q_bf, 1024, 1024, 1024, 1024, 0, 1, 1.0f, 8, 32};
        ga.g[1] = (GDesc){y_bf, w_k, bk, nullptr, K_bf, 1024, 1024, 1024, 1024, 0, 1, 1.0f, 8, 32};
        ga.g[2] = (GDesc){y_bf, w_v, bv, nullptr, V_bf, 1024, 1024, 1024, 1024, 0, 1, 1.0f, 8, 32};
        gemm_multi<<<dim3(8, 32, 3), blk, 0, stream>>>(ga);
    }
    // 9. S = Q @ K^T * scale
    gemm_batched<<<dim3(8, 8, 16), blk, 0, stream>>>(Q_bf, K_bf, Sbuf,
        DK, 1024, 1024, 1024,
        LL * 1024, 256, LL * 1024, 256,
        4 * LL * 1024, LL * 1024, 0.0625f);
    // 10. softmax
    softmax_rows<<<dim3(4096), blk, 0, stream>>>(Sbuf);
    // 11. V transpose
    transpose_v<<<dim3(32, 8, 16), blk, 0, stream>>>(V_bf, VT);
    // 12. AO = P @ V
    gemm_batched<<<dim3(2, 8, 16), blk, 0, stream>>>(Sbuf, VT, AO,
        1024, 1024, 1024, 1024,
        4 * LL * 1024, LL * 1024,
        4 * (long long)DK * 1024, (long long)DK * 1024,
        LL * 1024, 256, 1.0f);
    // 13. out = AO @ wo^T + bo (fp32)
    {
        GArgs ga = {};
        ga.g[0] = (GDesc){AO, w_o, bo, out, nullptr, 1024, 1024, 1024, 1024, 0, 0, 1.0f, 8, 32};
        gemm_multi<<<dim3(8, 32, 1), blk, 0, stream>>>(ga);
    }
}